// Round 8
// baseline (93.698 us; speedup 1.0000x reference)
//
#include <hip/hip_runtime.h>
#include <hip/hip_bf16.h>
#include <cstddef>
#include <cstdint>

namespace {

using f32x4  = __attribute__((ext_vector_type(4))) float;
using bf16x8 = __attribute__((ext_vector_type(8))) short;
using u16x4  = __attribute__((ext_vector_type(4))) unsigned short;

constexpr int TOTAL_BLOCKS = 5120;  // 1024 attn (bid%5==0) + 4096 prior (8 rows + 2 zfill units)
constexpr int PSTR = 1032;          // P LDS row stride (shorts); 2064B rows, 16B-aligned

__device__ inline unsigned short f2bf(float x) {
  __hip_bfloat16 hv = __float2bfloat16(x);
  return *reinterpret_cast<unsigned short*>(&hv);
}
__device__ inline float bf2f(unsigned short u) {
  return __uint_as_float(((unsigned int)u) << 16);
}
__device__ inline bf16x8 pack_bf8(f32x4 a, f32x4 b) {
  bf16x8 r;
  r[0] = (short)f2bf(a[0]); r[1] = (short)f2bf(a[1]);
  r[2] = (short)f2bf(a[2]); r[3] = (short)f2bf(a[3]);
  r[4] = (short)f2bf(b[0]); r[5] = (short)f2bf(b[1]);
  r[6] = (short)f2bf(b[2]); r[7] = (short)f2bf(b[3]);
  return r;
}
__device__ inline bf16x8 pack8(const float* p) {
  bf16x8 r;
#pragma unroll
  for (int i = 0; i < 8; ++i) r[i] = (short)f2bf(p[i]);
  return r;
}

__global__ __launch_bounds__(256) void fused_all(
    const float* __restrict__ Qg, const float* __restrict__ Kg,
    const float* __restrict__ Vg, const float* __restrict__ Sg,
    const float* __restrict__ sacg, const int* __restrict__ tg,
    float* __restrict__ outV, float* __restrict__ outS,
    float* __restrict__ outP, float* __restrict__ outT)
{
  __shared__ unsigned short Pl[32 * PSTR];   // unnormalized exp(scores), bf16: [q_local][s]
  __shared__ float red[4][32];
  __shared__ float invl[32];

  const int tid = threadIdx.x;
  const int bid = blockIdx.x;
  const int role5 = bid / 5;

  if (bid - role5 * 5 != 0) {
    // ------------- prior + sigma_t (streaming, 8 rows) + series zero-fill -------------
    const int pb = role5 * 4 + (bid - role5 * 5) - 1;   // 0..4095
    const int ln = tid & 63;
    const float sac = sacg[tg[(pb * 8) >> 13]];         // 8 rows never straddle a batch
#pragma unroll
    for (int rr = 0; rr < 2; ++rr) {
      const int r0 = pb * 8 + rr * 4 + (tid >> 6);      // global row in [B][H][L]
      const int b  = r0 >> 13;
      const int hh = (r0 >> 10) & 7;
      const int l  = r0 & 1023;
      const float sgv = Sg[(size_t)(b * 1024 + l) * 8 + hh];
      const float sig = 1.f / (1.f + __expf(-5.f * sgv)) + 1e-5f;
      const float st  = sac * expm1f(sig * 1.0986122886681098f);  // sac*(3^sig-1)
      const float coef = 0.3989422804014327f / st;
      const float qc   = -0.5f / (st * st);
      float* pp = outP + ((size_t)r0 << 10);
      float* tp = outT + ((size_t)r0 << 10);
      const f32x4 stv = {st, st, st, st};
      f32x4 prj[4];
#pragma unroll
      for (int j = 0; j < 4; ++j) {
        const int c0 = j * 256 + ln * 4;
        const float d0 = (float)(l - c0);
        const float d1 = d0 - 1.f, d2 = d0 - 2.f, d3 = d0 - 3.f;
        prj[j][0] = coef * __expf(qc * d0 * d0);
        prj[j][1] = coef * __expf(qc * d1 * d1);
        prj[j][2] = coef * __expf(qc * d2 * d2);
        prj[j][3] = coef * __expf(qc * d3 * d3);
      }
#pragma unroll
      for (int j = 0; j < 4; ++j)
        __builtin_nontemporal_store(prj[j], reinterpret_cast<f32x4*>(pp + j * 256 + ln * 4));
#pragma unroll
      for (int j = 0; j < 4; ++j)
        __builtin_nontemporal_store(stv, reinterpret_cast<f32x4*>(tp + j * 256 + ln * 4));
    }

    // series zero rectangles: 7680 units of 32 rows x 64 cols; pb<3840 handles 2
    if (pb < 3840) {
      const f32x4 z4 = {0.f, 0.f, 0.f, 0.f};
#pragma unroll
      for (int zz = 0; zz < 2; ++zz) {
        const int z  = pb * 2 + zz;                     // 0..7679
        const int bh = z / 240;
        const int r  = z - bh * 240;                    // 0..239
        // cumulative start of qt-pair i is C(i)=i*(31-i); find i with C(i)<=r<C(i+1)
        int i = (int)((31.0f - sqrtf((float)(961 - 4 * r))) * 0.5f);
        if (i > 0 && i * (31 - i) > r) --i;
        if ((i + 1) * (30 - i) <= r) ++i;
        const int off = r - i * (31 - i);
        const int w15 = 15 - i;                         // zero chunks per qt in this pair
        const int qt  = 2 * i + (off >= w15 ? 1 : 0);
        const int c   = (i + 1) + (off >= w15 ? off - w15 : off);
        const int row = tid >> 3;                       // 0..31
        float* p = outS + (((size_t)bh * 1024 + qt * 32 + row) << 10) + c * 64 + (tid & 7) * 8;
        __builtin_nontemporal_store(z4, reinterpret_cast<f32x4*>(p));
        __builtin_nontemporal_store(z4, reinterpret_cast<f32x4*>(p + 4));
      }
    }
    return;
  }

  // ---------------- attention: V + series triangle, single pass ----------------
  const int aid = role5;                     // 0..1023
  const int w = tid >> 6, ln = tid & 63;
  const int g = ln >> 4, n16 = ln & 15;
  const int bh = aid & 31, b = bh >> 3, h = bh & 7;
  const int qt = 31 - (aid >> 5);            // heavy tiles dispatched first
  const int qb = qt * 32;
  const int nch = (qt >> 1) + 1;             // 64-s chunks covering causal extent

  const float* Qbase = Qg + ((size_t)(b * 1024) * 8 + h) * 64;
  const float* Kbase = Kg + ((size_t)(b * 1024) * 8 + h) * 64;
  const float* Vbase = Vg + ((size_t)(b * 1024) * 8 + h) * 64;

  // Q B-fragments: lane holds Q[q = u*16 + n16][8g..8g+7] for each 32-k half
  bf16x8 qf[2][2];
#pragma unroll
  for (int u = 0; u < 2; ++u) {
    const float* qr = Qbase + (size_t)(qb + u * 16 + n16) * 512 + 8 * g;
    qf[u][0] = pack_bf8(*(const f32x4*)(qr),      *(const f32x4*)(qr + 4));
    qf[u][1] = pack_bf8(*(const f32x4*)(qr + 32), *(const f32x4*)(qr + 36));
  }

  f32x4 O[2] = {};                           // wave owns d-subtile w; O[u] = q-subtile u
  float cs[2] = {0.f, 0.f};

  // V columns for this wave's d-subtile: lane (g,n16) needs
  // V[s = c*64 + 32*h2 + 8*g + j][d = w*16 + n16], j = 0..7
  const float* vcol = Vbase + (size_t)(8 * g) * 512 + w * 16 + n16;

  float vrA[16], vrB[16];
  auto vload = [&](int c, float (&dst)[16]) {
    const float* p = vcol + (size_t)c * 64 * 512;
#pragma unroll
    for (int h2 = 0; h2 < 2; ++h2)
#pragma unroll
      for (int j = 0; j < 8; ++j)
        dst[h2 * 8 + j] = p[(size_t)(32 * h2 + j) * 512];
  };

  auto body = [&](int c, float (&vc)[16], float (&vn)[16]) {
    // K A-fragments for this wave's s-subtile (rows c*64 + w*16 + n16)
    const float* kr = Kbase + (size_t)(c * 64 + w * 16 + n16) * 512 + 8 * g;
    const bf16x8 kf0 = pack_bf8(*(const f32x4*)(kr),      *(const f32x4*)(kr + 4));
    const bf16x8 kf1 = pack_bf8(*(const f32x4*)(kr + 32), *(const f32x4*)(kr + 36));

    // QK^T (swapped: A=K rows s, B=Q cols q) -> exp (m=0) -> P LDS
#pragma unroll
    for (int u = 0; u < 2; ++u) {
      f32x4 acc = {0.f, 0.f, 0.f, 0.f};
      acc = __builtin_amdgcn_mfma_f32_16x16x32_bf16(kf0, qf[u][0], acc, 0, 0, 0);
      acc = __builtin_amdgcn_mfma_f32_16x16x32_bf16(kf1, qf[u][1], acc, 0, 0, 0);
      const int qlane = qb + u * 16 + n16;
      const int sbase = c * 64 + w * 16 + 4 * g;
      const float e0 = (sbase + 0 <= qlane) ? __expf(acc[0] * 0.125f) : 0.f;
      const float e1 = (sbase + 1 <= qlane) ? __expf(acc[1] * 0.125f) : 0.f;
      const float e2 = (sbase + 2 <= qlane) ? __expf(acc[2] * 0.125f) : 0.f;
      const float e3 = (sbase + 3 <= qlane) ? __expf(acc[3] * 0.125f) : 0.f;
      cs[u] += (e0 + e1) + (e2 + e3);
      u16x4 pk = {f2bf(e0), f2bf(e1), f2bf(e2), f2bf(e3)};
      *reinterpret_cast<u16x4*>(&Pl[(u * 16 + n16) * PSTR + sbase]) = pk;
    }

    if (c + 1 < nch) vload(c + 1, vn);       // prefetch next chunk's V columns

    __syncthreads();                         // P columns of chunk c visible

    // PV: A = P rows q (from Pl), B = V cols d (registers)
    const bf16x8 vv0 = pack8(&vc[0]);
    const bf16x8 vv1 = pack8(&vc[8]);
#pragma unroll
    for (int u = 0; u < 2; ++u) {
      const bf16x8 pa0 =
          *reinterpret_cast<const bf16x8*>(&Pl[(u * 16 + n16) * PSTR + c * 64 + 8 * g]);
      O[u] = __builtin_amdgcn_mfma_f32_16x16x32_bf16(pa0, vv0, O[u], 0, 0, 0);
      const bf16x8 pa1 =
          *reinterpret_cast<const bf16x8*>(&Pl[(u * 16 + n16) * PSTR + c * 64 + 32 + 8 * g]);
      O[u] = __builtin_amdgcn_mfma_f32_16x16x32_bf16(pa1, vv1, O[u], 0, 0, 0);
    }
  };

  vload(0, vrA);
  int c = 0;
  while (true) {
    body(c, vrA, vrB);
    if (++c >= nch) break;
    body(c, vrB, vrA);
    if (++c >= nch) break;
  }

  // row sums -> invl
  cs[0] += __shfl_xor(cs[0], 16); cs[0] += __shfl_xor(cs[0], 32);
  cs[1] += __shfl_xor(cs[1], 16); cs[1] += __shfl_xor(cs[1], 32);
  if (ln < 16) { red[w][n16] = cs[0]; red[w][16 + n16] = cs[1]; }
  __syncthreads();
  if (tid < 32) {
    const float s = red[0][tid] + red[1][tid] + red[2][tid] + red[3][tid];
    invl[tid] = 1.f / s;
  }
  __syncthreads();

  // V output: rows q = qb + u*16 + 4g + r, col d = w*16 + n16
  {
    float* Vo = outV + ((size_t)(b * 1024) * 8 + h) * 64;
#pragma unroll
    for (int u = 0; u < 2; ++u)
#pragma unroll
      for (int r = 0; r < 4; ++r) {
        const int qrow = u * 16 + 4 * g + r;
        __builtin_nontemporal_store(O[u][r] * invl[qrow],
                                    Vo + (size_t)(qb + qrow) * 512 + w * 16 + n16);
      }
  }

  // series output (triangle only: cols < nch*64): coalesced f32x4 rows from Pl * invl
  {
    const int r = tid >> 3, sub = tid & 7;
    float* Srow = outS + ((size_t)bh * 1024 + qb + r) * 1024;
    const float il = invl[r];
    const int jmax = nch << 1;               // each j covers 32 cols
#pragma unroll 4
    for (int j = 0; j < jmax; ++j) {
      const int s = j * 32 + sub * 4;
      const u16x4 p = *reinterpret_cast<const u16x4*>(&Pl[r * PSTR + s]);
      f32x4 o;
      o[0] = bf2f(p[0]) * il;
      o[1] = bf2f(p[1]) * il;
      o[2] = bf2f(p[2]) * il;
      o[3] = bf2f(p[3]) * il;
      __builtin_nontemporal_store(o, reinterpret_cast<f32x4*>(Srow + s));
    }
  }
}

}  // namespace

extern "C" void kernel_launch(void* const* d_in, const int* in_sizes, int n_in,
                              void* d_out, int out_size, void* d_ws, size_t ws_size,
                              hipStream_t stream) {
  const float* Qg   = (const float*)d_in[0];
  const float* Kg   = (const float*)d_in[1];
  const float* Vg   = (const float*)d_in[2];
  const float* Sg   = (const float*)d_in[3];
  const float* sacg = (const float*)d_in[4];
  const int*   tg   = (const int*)d_in[5];

  float* out  = (float*)d_out;
  float* outV = out;                       // [B,L,H,D]  = 2097152
  float* outS = out + (size_t)2097152;     // [B,H,L,S]  = 33554432
  float* outP = out + (size_t)35651584;    // prior
  float* outT = out + (size_t)69206016;    // sigma_t

  hipLaunchKernelGGL(fused_all, dim3(TOTAL_BLOCKS), dim3(256), 0, stream,
                     Qg, Kg, Vg, Sg, sacg, tg, outV, outS, outP, outT);
}

// Round 9
// 80.424 us; speedup vs baseline: 1.1650x; 1.1650x over previous
//
#include <hip/hip_runtime.h>
#include <hip/hip_bf16.h>
#include <cstddef>
#include <cstdint>

namespace {

using f32x4  = __attribute__((ext_vector_type(4))) float;
using bf16x8 = __attribute__((ext_vector_type(8))) short;
using u16x4  = __attribute__((ext_vector_type(4))) unsigned short;

constexpr int TOTAL_BLOCKS = 5120;  // 1024 attn (bid%5==0) + 4096 prior (8 rows each)
constexpr int PSTR = 1032;          // P LDS row stride (shorts); 2064B rows, 16B-aligned

__device__ inline unsigned short f2bf(float x) {
  __hip_bfloat16 hv = __float2bfloat16(x);
  return *reinterpret_cast<unsigned short*>(&hv);
}
__device__ inline float bf2f(unsigned short u) {
  return __uint_as_float(((unsigned int)u) << 16);
}
__device__ inline bf16x8 pack_bf8(f32x4 a, f32x4 b) {
  bf16x8 r;
  r[0] = (short)f2bf(a[0]); r[1] = (short)f2bf(a[1]);
  r[2] = (short)f2bf(a[2]); r[3] = (short)f2bf(a[3]);
  r[4] = (short)f2bf(b[0]); r[5] = (short)f2bf(b[1]);
  r[6] = (short)f2bf(b[2]); r[7] = (short)f2bf(b[3]);
  return r;
}
__device__ inline bf16x8 pack8(const float* p) {
  bf16x8 r;
#pragma unroll
  for (int i = 0; i < 8; ++i) r[i] = (short)f2bf(p[i]);
  return r;
}

__global__ __launch_bounds__(256) void fused_all(
    const float* __restrict__ Qg, const float* __restrict__ Kg,
    const float* __restrict__ Vg, const float* __restrict__ Sg,
    const float* __restrict__ sacg, const int* __restrict__ tg,
    float* __restrict__ outV, float* __restrict__ outS,
    float* __restrict__ outP, float* __restrict__ outT)
{
  __shared__ unsigned short Pl[32 * PSTR];   // unnormalized exp(scores), bf16: [q_local][s]
  __shared__ float red[4][32];
  __shared__ float invl[32];

  const int tid = threadIdx.x;
  const int bid = blockIdx.x;
  const int role5 = bid / 5;

  if (bid - role5 * 5 != 0) {
    // ------------- prior + sigma_t (pure streaming, interleaved, 8 rows) -------------
    const int pb = role5 * 4 + (bid - role5 * 5) - 1;   // 0..4095
    const int ln = tid & 63;
    const float sac = sacg[tg[(pb * 8) >> 13]];         // 8 rows never straddle a batch
#pragma unroll
    for (int rr = 0; rr < 2; ++rr) {
      const int r0 = pb * 8 + rr * 4 + (tid >> 6);      // global row in [B][H][L]
      const int b  = r0 >> 13;
      const int hh = (r0 >> 10) & 7;
      const int l  = r0 & 1023;
      const float sgv = Sg[(size_t)(b * 1024 + l) * 8 + hh];
      const float sig = 1.f / (1.f + __expf(-5.f * sgv)) + 1e-5f;
      const float st  = sac * expm1f(sig * 1.0986122886681098f);  // sac*(3^sig-1)
      const float coef = 0.3989422804014327f / st;
      const float qc   = -0.5f / (st * st);
      float* pp = outP + ((size_t)r0 << 10);
      float* tp = outT + ((size_t)r0 << 10);
      const f32x4 stv = {st, st, st, st};
#pragma unroll
      for (int j = 0; j < 4; ++j) {
        const int c0 = j * 256 + ln * 4;
        const float d0 = (float)(l - c0);
        const float d1 = d0 - 1.f, d2 = d0 - 2.f, d3 = d0 - 3.f;
        f32x4 pr;
        pr[0] = coef * __expf(qc * d0 * d0);
        pr[1] = coef * __expf(qc * d1 * d1);
        pr[2] = coef * __expf(qc * d2 * d2);
        pr[3] = coef * __expf(qc * d3 * d3);
        __builtin_nontemporal_store(pr, reinterpret_cast<f32x4*>(pp + c0));
        __builtin_nontemporal_store(stv, reinterpret_cast<f32x4*>(tp + c0));
      }
    }
    return;
  }

  // ---------------- attention: V + series, single pass, 1 barrier/chunk ----------------
  const int aid = role5;                     // 0..1023
  const int w = tid >> 6, ln = tid & 63;
  const int g = ln >> 4, n16 = ln & 15;
  const int bh = aid & 31, b = bh >> 3, h = bh & 7;
  const int qt = 31 - (aid >> 5);            // heavy tiles dispatched first
  const int qb = qt * 32;
  const int nch = (qt >> 1) + 1;             // 64-s chunks covering causal extent

  const float* Qbase = Qg + ((size_t)(b * 1024) * 8 + h) * 64;
  const float* Kbase = Kg + ((size_t)(b * 1024) * 8 + h) * 64;
  const float* Vbase = Vg + ((size_t)(b * 1024) * 8 + h) * 64;

  // Q B-fragments: lane holds Q[q = u*16 + n16][8g..8g+7] for each 32-k half
  bf16x8 qf[2][2];
#pragma unroll
  for (int u = 0; u < 2; ++u) {
    const float* qr = Qbase + (size_t)(qb + u * 16 + n16) * 512 + 8 * g;
    qf[u][0] = pack_bf8(*(const f32x4*)(qr),      *(const f32x4*)(qr + 4));
    qf[u][1] = pack_bf8(*(const f32x4*)(qr + 32), *(const f32x4*)(qr + 36));
  }

  f32x4 O[2] = {};                           // wave owns d-subtile w; O[u] = q-subtile u
  float cs[2] = {0.f, 0.f};

  // V columns for this wave's d-subtile: lane (g,n16) needs
  // V[s = c*64 + 32*h2 + 8*g + j][d = w*16 + n16], j = 0..7
  const float* vcol = Vbase + (size_t)(8 * g) * 512 + w * 16 + n16;

  float vrA[16], vrB[16];
  auto vload = [&](int c, float (&dst)[16]) {
    const float* p = vcol + (size_t)c * 64 * 512;
#pragma unroll
    for (int h2 = 0; h2 < 2; ++h2)
#pragma unroll
      for (int j = 0; j < 8; ++j)
        dst[h2 * 8 + j] = p[(size_t)(32 * h2 + j) * 512];
  };

  auto body = [&](int c, float (&vc)[16], float (&vn)[16]) {
    // K A-fragments for this wave's s-subtile (rows c*64 + w*16 + n16)
    const float* kr = Kbase + (size_t)(c * 64 + w * 16 + n16) * 512 + 8 * g;
    const bf16x8 kf0 = pack_bf8(*(const f32x4*)(kr),      *(const f32x4*)(kr + 4));
    const bf16x8 kf1 = pack_bf8(*(const f32x4*)(kr + 32), *(const f32x4*)(kr + 36));

    // QK^T (swapped: A=K rows s, B=Q cols q) -> exp (m=0) -> P LDS
#pragma unroll
    for (int u = 0; u < 2; ++u) {
      f32x4 acc = {0.f, 0.f, 0.f, 0.f};
      acc = __builtin_amdgcn_mfma_f32_16x16x32_bf16(kf0, qf[u][0], acc, 0, 0, 0);
      acc = __builtin_amdgcn_mfma_f32_16x16x32_bf16(kf1, qf[u][1], acc, 0, 0, 0);
      const int qlane = qb + u * 16 + n16;
      const int sbase = c * 64 + w * 16 + 4 * g;
      const float e0 = (sbase + 0 <= qlane) ? __expf(acc[0] * 0.125f) : 0.f;
      const float e1 = (sbase + 1 <= qlane) ? __expf(acc[1] * 0.125f) : 0.f;
      const float e2 = (sbase + 2 <= qlane) ? __expf(acc[2] * 0.125f) : 0.f;
      const float e3 = (sbase + 3 <= qlane) ? __expf(acc[3] * 0.125f) : 0.f;
      cs[u] += (e0 + e1) + (e2 + e3);
      u16x4 pk = {f2bf(e0), f2bf(e1), f2bf(e2), f2bf(e3)};
      *reinterpret_cast<u16x4*>(&Pl[(u * 16 + n16) * PSTR + sbase]) = pk;
    }

    if (c + 1 < nch) vload(c + 1, vn);       // prefetch next chunk's V columns

    __syncthreads();                         // P columns of chunk c visible

    // PV: A = P rows q (from Pl), B = V cols d (registers)
    const bf16x8 vv0 = pack8(&vc[0]);
    const bf16x8 vv1 = pack8(&vc[8]);
#pragma unroll
    for (int u = 0; u < 2; ++u) {
      const bf16x8 pa0 =
          *reinterpret_cast<const bf16x8*>(&Pl[(u * 16 + n16) * PSTR + c * 64 + 8 * g]);
      O[u] = __builtin_amdgcn_mfma_f32_16x16x32_bf16(pa0, vv0, O[u], 0, 0, 0);
      const bf16x8 pa1 =
          *reinterpret_cast<const bf16x8*>(&Pl[(u * 16 + n16) * PSTR + c * 64 + 32 + 8 * g]);
      O[u] = __builtin_amdgcn_mfma_f32_16x16x32_bf16(pa1, vv1, O[u], 0, 0, 0);
    }
  };

  vload(0, vrA);
  int c = 0;
  while (true) {
    body(c, vrA, vrB);
    if (++c >= nch) break;
    body(c, vrB, vrA);
    if (++c >= nch) break;
  }

  // row sums -> invl
  cs[0] += __shfl_xor(cs[0], 16); cs[0] += __shfl_xor(cs[0], 32);
  cs[1] += __shfl_xor(cs[1], 16); cs[1] += __shfl_xor(cs[1], 32);
  if (ln < 16) { red[w][n16] = cs[0]; red[w][16 + n16] = cs[1]; }
  __syncthreads();
  if (tid < 32) {
    const float s = red[0][tid] + red[1][tid] + red[2][tid] + red[3][tid];
    invl[tid] = 1.f / s;
  }
  __syncthreads();

  // V output: rows q = qb + u*16 + 4g + r, col d = w*16 + n16
  {
    float* Vo = outV + ((size_t)(b * 1024) * 8 + h) * 64;
#pragma unroll
    for (int u = 0; u < 2; ++u)
#pragma unroll
      for (int r = 0; r < 4; ++r) {
        const int qrow = u * 16 + 4 * g + r;
        __builtin_nontemporal_store(O[u][r] * invl[qrow],
                                    Vo + (size_t)(qb + qrow) * 512 + w * 16 + n16);
      }
  }

  // series output: row-sequential; per instruction 64 lanes x f32x4 = 1KB contiguous
  {
    const int slim = nch << 6;
#pragma unroll
    for (int i = 0; i < 8; ++i) {
      const int r = w * 8 + i;                 // wave owns 8 consecutive rows
      float* Srow = outS + ((size_t)bh * 1024 + qb + r) * 1024;
      const float il = invl[r];
      const unsigned short* Prow = &Pl[r * PSTR];
#pragma unroll
      for (int rep = 0; rep < 4; ++rep) {
        const int s = rep * 256 + ln * 4;
        f32x4 o = {0.f, 0.f, 0.f, 0.f};
        if (s < slim) {                        // slim%64==0, s%4==0 -> whole quad in-range
          const u16x4 p = *reinterpret_cast<const u16x4*>(&Prow[s]);
          o[0] = bf2f(p[0]) * il;
          o[1] = bf2f(p[1]) * il;
          o[2] = bf2f(p[2]) * il;
          o[3] = bf2f(p[3]) * il;
        }
        __builtin_nontemporal_store(o, reinterpret_cast<f32x4*>(Srow + s));
      }
    }
  }
}

}  // namespace

extern "C" void kernel_launch(void* const* d_in, const int* in_sizes, int n_in,
                              void* d_out, int out_size, void* d_ws, size_t ws_size,
                              hipStream_t stream) {
  const float* Qg   = (const float*)d_in[0];
  const float* Kg   = (const float*)d_in[1];
  const float* Vg   = (const float*)d_in[2];
  const float* Sg   = (const float*)d_in[3];
  const float* sacg = (const float*)d_in[4];
  const int*   tg   = (const int*)d_in[5];

  float* out  = (float*)d_out;
  float* outV = out;                       // [B,L,H,D]  = 2097152
  float* outS = out + (size_t)2097152;     // [B,H,L,S]  = 33554432
  float* outP = out + (size_t)35651584;    // prior
  float* outT = out + (size_t)69206016;    // sigma_t

  hipLaunchKernelGGL(fused_all, dim3(TOTAL_BLOCKS), dim3(256), 0, stream,
                     Qg, Kg, Vg, Sg, sacg, tg, outV, outS, outP, outT);
}